// Round 1
// baseline (115.007 us; speedup 1.0000x reference)
//
#include <hip/hip_runtime.h>
#include <math.h>

#define NPOS 4096   // H*W
#define NB   4      // batch
#define NROW (NB * NPOS)
#define LOG2E 1.44269504088896f

typedef _Float16 f16;
typedef f16 f16x4 __attribute__((ext_vector_type(4)));
typedef f16 f16x8 __attribute__((ext_vector_type(8)));
typedef float f32x4 __attribute__((ext_vector_type(4)));
typedef float f32x16 __attribute__((ext_vector_type(16)));

// ---------------------------------------------------------------------------
// Kernel 1: QKV projection as MFMA GEMM (unchanged from 116.5us champion).
// q pre-scaled by log2(e); pos bias folded into k; v stored [c][n].
// ---------------------------------------------------------------------------
#define LDW 72

__global__ __launch_bounds__(256) void qkv_proj(
    const float* __restrict__ x,
    const float* __restrict__ Wq, const float* __restrict__ bq,
    const float* __restrict__ Wk, const float* __restrict__ bk,
    const float* __restrict__ Wv, const float* __restrict__ bv,
    const float* __restrict__ rel_h, const float* __restrict__ rel_w,
    f16* __restrict__ qh, f16* __restrict__ kh, f16* __restrict__ vh)
{
    __shared__ __align__(16) f16 Ws[192 * LDW];  // [o_all][c]
    __shared__ __align__(16) f16 Xs[32 * LDW];   // [n_local][c]
    __shared__ __align__(16) f16 Vs[64 * 36];    // v transpose buffer [c][n_local]

    const int tid = threadIdx.x;
    const int b   = blockIdx.x >> 7;           // 128 tiles per batch
    const int n0  = (blockIdx.x & 127) << 5;   // 32-position tile

    #pragma unroll
    for (int k = 0; k < 12; ++k) {
        int idx  = tid + k * 256;
        int orow = idx >> 4;
        int cseg = (idx & 15) << 2;
        int mat  = orow >> 6;
        int o    = orow & 63;
        const float* wsrc = (mat == 0) ? Wq : ((mat == 1) ? Wk : Wv);
        float4 v = *(const float4*)(wsrc + o * 64 + cseg);
        f16x4 h; h[0] = (f16)v.x; h[1] = (f16)v.y; h[2] = (f16)v.z; h[3] = (f16)v.w;
        *(f16x4*)(&Ws[orow * LDW + cseg]) = h;
    }
    {
        int c  = tid >> 2;
        int ns = (tid & 3) << 3;
        const float* xp = x + ((size_t)(b * 64 + c)) * NPOS + n0 + ns;
        float4 v0 = *(const float4*)(xp);
        float4 v1 = *(const float4*)(xp + 4);
        Xs[(ns + 0) * LDW + c] = (f16)v0.x;
        Xs[(ns + 1) * LDW + c] = (f16)v0.y;
        Xs[(ns + 2) * LDW + c] = (f16)v0.z;
        Xs[(ns + 3) * LDW + c] = (f16)v0.w;
        Xs[(ns + 4) * LDW + c] = (f16)v1.x;
        Xs[(ns + 5) * LDW + c] = (f16)v1.y;
        Xs[(ns + 6) * LDW + c] = (f16)v1.z;
        Xs[(ns + 7) * LDW + c] = (f16)v1.w;
    }
    __syncthreads();

    const int wave = tid >> 6;
    const int lane = tid & 63;
    const int quad = lane >> 4;
    const int l16  = lane & 15;
    const int rg   = wave >> 1;                // row-group (16 n each)
    const int tb   = (wave & 1) * 6;           // out-tile base

    const f16x8 a0 = *(const f16x8*)(&Xs[(rg * 16 + l16) * LDW + quad * 8]);
    const f16x8 a1 = *(const f16x8*)(&Xs[(rg * 16 + l16) * LDW + 32 + quad * 8]);

    f32x4 acc[6];
    #pragma unroll
    for (int i = 0; i < 6; ++i) {
        int t = tb + i;
        f32x4 c0 = {0, 0, 0, 0};
        f16x8 b0 = *(const f16x8*)(&Ws[(t * 16 + l16) * LDW + quad * 8]);
        f16x8 b1 = *(const f16x8*)(&Ws[(t * 16 + l16) * LDW + 32 + quad * 8]);
        c0 = __builtin_amdgcn_mfma_f32_16x16x32_f16(a0, b0, c0, 0, 0, 0);
        c0 = __builtin_amdgcn_mfma_f32_16x16x32_f16(a1, b1, c0, 0, 0, 0);
        acc[i] = c0;
    }

    #pragma unroll
    for (int i = 0; i < 6; ++i) {
        int t = tb + i;
        if (t < 4) {                       // q tiles
            int o = t * 16 + l16;
            float bb = bq[o];
            #pragma unroll
            for (int r = 0; r < 4; ++r) {
                size_t n = (size_t)b * NPOS + n0 + rg * 16 + quad * 4 + r;
                qh[n * 64 + o] = (f16)((acc[i][r] + bb) * LOG2E);
            }
        } else if (t < 8) {                // k tiles (+ positional bias)
            int o = (t - 4) * 16 + l16;
            int h = n0 >> 6;
            int wbase = (n0 & 63) + rg * 16;
            float bb = bk[o] + rel_h[o * 64 + h];
            #pragma unroll
            for (int r = 0; r < 4; ++r) {
                size_t n = (size_t)b * NPOS + n0 + rg * 16 + quad * 4 + r;
                kh[n * 64 + o] = (f16)(acc[i][r] + bb + rel_w[o * 64 + wbase + quad * 4 + r]);
            }
        } else {                           // v tiles -> LDS transpose
            int o = (t - 8) * 16 + l16;
            float bb = bv[o];
            #pragma unroll
            for (int r = 0; r < 4; ++r)
                Vs[o * 36 + rg * 16 + quad * 4 + r] = (f16)(acc[i][r] + bb);
        }
    }
    __syncthreads();
    {
        int c  = tid >> 2;
        int ns = (tid & 3) << 3;
        f16x8 vv = *(const f16x8*)(&Vs[c * 36 + ns]);
        *(f16x8*)(vh + ((size_t)(b * 64 + c)) * NPOS + n0 + ns) = vv;
    }
}

// ---------------------------------------------------------------------------
// Kernel 2 (round 10): full-rate 32x32x16 restructure.
//   S^T = K Q^T with col = n  ->  O^T = V^T P with col = n.
//   Softmax stats (m,l,alpha) are per-lane (column) -> zero shuffles except
//   one shfl_xor(32) per reduction. P feeds PV's B-frag in register order:
//   the k->m permutation {0-3,8-11,4-7,12-15} is absorbed into V's A-frag
//   reads (two b64 per fragment). LDS: unpadded [64][64] tiles, XOR-swizzled
//   (slot ^= row&7), filled by global_load_lds width=16 with linear dest +
//   inverse-swizzled per-lane global source (m201/m173 pattern).
//   LDS 32 KiB -> 4 blocks/CU; 128 MFMA / wave / 128-m iter (was 384).
// ---------------------------------------------------------------------------
__global__ __launch_bounds__(256, 4) void attn(
    const f16* __restrict__ qh, const f16* __restrict__ kh,
    const f16* __restrict__ vh,
    f16* __restrict__ Op, float* __restrict__ Mp, float* __restrict__ Lp,
    int split, int mchunk)
{
    __shared__ __align__(16) f16 Ks[2][64 * 64];   // [m_local][c], swizzled
    __shared__ __align__(16) f16 Vt[2][64 * 64];   // [c][m_local], swizzled

    const int tid  = threadIdx.x;
    const int wv   = tid >> 6;
    const int lane = tid & 63;
    const int l31  = lane & 31;
    const int hi   = lane >> 5;
    const int sw   = l31 & 7;
    const int s    = blockIdx.x % split;
    const int tile = blockIdx.x / split;
    const int b    = tile >> 5;                 // 32 tiles of 128 n per batch
    const int n0   = (tile & 31) << 7;
    const int n_lane = n0 + wv * 32 + l31;

    // Q B-fragments: B[k=hi*8+j][col=n] = Q[n][kc*16 + hi*8 + j]
    f16x8 bq[4];
    {
        const f16* qbase = qh + ((size_t)b * NPOS + n_lane) * 64 + hi * 8;
        #pragma unroll
        for (int kc = 0; kc < 4; ++kc) bq[kc] = *(const f16x8*)(qbase + kc * 16);
    }

    f32x16 O0 = {}, O1 = {};            // O^T tiles: c 0..31 / 32..63
    float m_i = -1e30f, l_i = 0.f;

    const f16* kb = kh + (size_t)b * NPOS * 64;
    const f16* vb = vh + (size_t)b * 64 * NPOS;

    const int m_begin = s * mchunk;
    for (int m0 = m_begin; m0 < m_begin + mchunk; m0 += 128) {
        // async stage both 64-m halves of K and V
        #pragma unroll
        for (int h = 0; h < 2; ++h) {
            #pragma unroll
            for (int q = 0; q < 2; ++q) {
                const int idx  = q * 256 + tid;
                const int row  = idx >> 3;                 // 0..63
                const int slot = (idx & 7) ^ (row & 7);    // inverse swizzle on src
                __builtin_amdgcn_global_load_lds(
                    (const __attribute__((address_space(1))) void*)
                        (kb + (size_t)(m0 + h * 64 + row) * 64 + slot * 8),
                    (__attribute__((address_space(3))) void*)
                        (&Ks[h][(q * 4 + wv) * 512]),
                    16, 0, 0);
                __builtin_amdgcn_global_load_lds(
                    (const __attribute__((address_space(1))) void*)
                        (vb + (size_t)row * NPOS + m0 + h * 64 + slot * 8),
                    (__attribute__((address_space(3))) void*)
                        (&Vt[h][(q * 4 + wv) * 512]),
                    16, 0, 0);
            }
        }
        __syncthreads();   // drains vmcnt -> LDS tiles complete

        #pragma unroll
        for (int h = 0; h < 2; ++h) {
            // S^T = K Q^T : two 32-m tiles, col = n = l31 (hi-pairs share col)
            f32x16 S0 = {}, S1 = {};
            #pragma unroll
            for (int kc = 0; kc < 4; ++kc) {
                const int so = ((kc * 2 + hi) ^ sw) << 3;
                f16x8 ak0 = *(const f16x8*)(&Ks[h][l31 * 64 + so]);
                f16x8 ak1 = *(const f16x8*)(&Ks[h][(32 + l31) * 64 + so]);
                S0 = __builtin_amdgcn_mfma_f32_32x32x16_f16(ak0, bq[kc], S0, 0, 0, 0);
                S1 = __builtin_amdgcn_mfma_f32_32x32x16_f16(ak1, bq[kc], S1, 0, 0, 0);
            }

            // column max: tree over own 32 regs + partner half
            float tm[8];
            #pragma unroll
            for (int r = 0; r < 8; ++r)
                tm[r] = fmaxf(fmaxf(S0[r], S0[r + 8]), fmaxf(S1[r], S1[r + 8]));
            #pragma unroll
            for (int st = 4; st > 0; st >>= 1)
                #pragma unroll
                for (int r = 0; r < st; ++r) tm[r] = fmaxf(tm[r], tm[r + st]);
            float mx = fmaxf(tm[0], __shfl_xor(tm[0], 32));

            if (__any(mx > m_i)) {          // per-lane alpha, no broadcasts
                const float mn = fmaxf(m_i, mx);
                const float al = __builtin_amdgcn_exp2f(m_i - mn);
                m_i = mn;
                l_i *= al;
                #pragma unroll
                for (int r = 0; r < 16; ++r) { O0[r] *= al; O1[r] *= al; }
            }

            // exp + pack (register order == B-frag order) + PV per 16-m chunk
            float rs = 0.f;
            #pragma unroll
            for (int mc = 0; mc < 4; ++mc) {
                f16x8 pb;
                #pragma unroll
                for (int j = 0; j < 8; ++j) {
                    const float sv = (mc < 2) ? S0[(mc & 1) * 8 + j]
                                              : S1[(mc & 1) * 8 + j];
                    const float e = __builtin_amdgcn_exp2f(sv - m_i);
                    rs += e;
                    pb[j] = (f16)e;
                }
                // V A-frag: k->m permutation via two b64 reads
                const int s0off = (((mc * 2)     ^ sw) << 3) + (hi << 2);
                const int s1off = (((mc * 2 + 1) ^ sw) << 3) + (hi << 2);
                {
                    const f16* vrow = &Vt[h][l31 * 64];
                    union { f16x8 v8; f16x4 v4[2]; } av;
                    av.v4[0] = *(const f16x4*)(vrow + s0off);
                    av.v4[1] = *(const f16x4*)(vrow + s1off);
                    O0 = __builtin_amdgcn_mfma_f32_32x32x16_f16(av.v8, pb, O0, 0, 0, 0);
                }
                {
                    const f16* vrow = &Vt[h][(32 + l31) * 64];
                    union { f16x8 v8; f16x4 v4[2]; } av;
                    av.v4[0] = *(const f16x4*)(vrow + s0off);
                    av.v4[1] = *(const f16x4*)(vrow + s1off);
                    O1 = __builtin_amdgcn_mfma_f32_32x32x16_f16(av.v8, pb, O1, 0, 0, 0);
                }
            }
            rs += __shfl_xor(rs, 32);
            l_i += rs;
        }
        __syncthreads();
    }

    // epilogue: per-lane 1/l (col = n), store O^T into Op[s][b][c][n]
    const float inv = 1.f / l_i;
    f16* opb = Op + (((size_t)s * NB + b) * 64) * NPOS + n_lane;
    #pragma unroll
    for (int r = 0; r < 16; ++r) {
        const int c0 = (r & 3) + ((r >> 2) << 3) + (hi << 2);
        opb[(size_t)c0 * NPOS]        = (f16)(O0[r] * inv);
        opb[(size_t)(c0 + 32) * NPOS] = (f16)(O1[r] * inv);
    }
    if (hi == 0) {
        const size_t row = (size_t)b * NPOS + n_lane;
        Mp[(size_t)s * NROW + row] = m_i;
        Lp[(size_t)s * NROW + row] = l_i;
    }
}

// ---------------------------------------------------------------------------
// Kernel 3: combine split partials over Op[s][b][c][n]. 32-n x 64-c tiles,
// grid 512; weights staged/normalized in LDS, f16x8 streaming reads.
// ---------------------------------------------------------------------------
__global__ __launch_bounds__(256) void combine(
    const f16* __restrict__ Op, const float* __restrict__ Mp,
    const float* __restrict__ Lp, float* __restrict__ out, int split)
{
    __shared__ float Wn[8][32];

    const int tid = threadIdx.x;
    const int b   = blockIdx.x >> 7;            // 128 tiles of 32 n per batch
    const int n0  = (blockIdx.x & 127) << 5;

    if (tid < 32) {
        const size_t row = (size_t)b * NPOS + n0 + tid;
        float M = -1e30f;
        for (int s2 = 0; s2 < split; ++s2)
            M = fmaxf(M, Mp[(size_t)s2 * NROW + row]);
        float L = 0.f;
        for (int s2 = 0; s2 < split; ++s2) {
            const float w = Lp[(size_t)s2 * NROW + row] *
                            __builtin_amdgcn_exp2f(Mp[(size_t)s2 * NROW + row] - M);
            Wn[s2][tid] = w;
            L += w;
        }
        const float inv = 1.f / L;
        for (int s2 = 0; s2 < split; ++s2) Wn[s2][tid] *= inv;
    }
    __syncthreads();

    const int c  = tid >> 2;
    const int ns = (tid & 3) << 3;
    float acc[8] = {0.f, 0.f, 0.f, 0.f, 0.f, 0.f, 0.f, 0.f};
    for (int s2 = 0; s2 < split; ++s2) {
        const f16x8 a = *(const f16x8*)(Op + (((size_t)s2 * NB + b) * 64 + c) * NPOS + n0 + ns);
        #pragma unroll
        for (int j = 0; j < 8; ++j) acc[j] += Wn[s2][ns + j] * (float)a[j];
    }
    float* po = out + ((size_t)(b * 64 + c)) * NPOS + n0 + ns;
    float4 o0 = {acc[0], acc[1], acc[2], acc[3]};
    float4 o1 = {acc[4], acc[5], acc[6], acc[7]};
    *(float4*)(po)     = o0;
    *(float4*)(po + 4) = o1;
}

// ---------------------------------------------------------------------------
extern "C" void kernel_launch(void* const* d_in, const int* in_sizes, int n_in,
                              void* d_out, int out_size, void* d_ws, size_t ws_size,
                              hipStream_t stream) {
    const float* x     = (const float*)d_in[0];
    const float* Wq    = (const float*)d_in[1];
    const float* bq    = (const float*)d_in[2];
    const float* Wk    = (const float*)d_in[3];
    const float* bk    = (const float*)d_in[4];
    const float* Wv    = (const float*)d_in[5];
    const float* bv    = (const float*)d_in[6];
    const float* rel_h = (const float*)d_in[7];
    const float* rel_w = (const float*)d_in[8];
    float* out = (float*)d_out;

    const size_t qkv_elems = (size_t)NROW * 64;
    int split = 8;
    {
        size_t need = 3 * qkv_elems * sizeof(f16)
                    + (size_t)split * NROW * 64 * sizeof(f16)
                    + 2 * (size_t)split * NROW * sizeof(float);
        if (ws_size < need) split = 4;     // deterministic wrt ws_size
    }
    const int mchunk = NPOS / split;       // multiple of 128

    f16* qh = (f16*)d_ws;
    f16* kh = qh + qkv_elems;
    f16* vh = kh + qkv_elems;
    f16* Op = vh + qkv_elems;
    float* Mp = (float*)(Op + (size_t)split * NROW * 64);
    float* Lp = Mp + (size_t)split * NROW;

    qkv_proj<<<NB * (NPOS / 32), 256, 0, stream>>>(x, Wq, bq, Wk, bk, Wv, bv,
                                                   rel_h, rel_w, qh, kh, vh);
    attn<<<NB * (NPOS / 128) * split, 256, 0, stream>>>(qh, kh, vh, Op, Mp, Lp,
                                                        split, mchunk);
    combine<<<NB * (NPOS / 32), 256, 0, stream>>>(Op, Mp, Lp, out, split);
}